// Round 4
// baseline (190.102 us; speedup 1.0000x reference)
//
#include <hip/hip_runtime.h>
#include <hip/hip_bf16.h>
#include <stdint.h>

#define N_NODES 50000
#define NE      1600000
#define DIM     128
#define HID     64

// ---------------- JAX threefry2x32 core (bit-exact) ----------------
struct TF2 { uint32_t a, b; };

__host__ __device__ constexpr uint32_t rotl32(uint32_t x, int d) {
  return (x << d) | (x >> (32 - d));
}

__host__ __device__ constexpr TF2 threefry(uint32_t k0, uint32_t k1,
                                           uint32_t c0, uint32_t c1) {
  uint32_t ks[3] = { k0, k1, k0 ^ k1 ^ 0x1BD11BDAu };
  uint32_t x0 = c0 + ks[0], x1 = c1 + ks[1];
  const int rot[2][4] = { {13, 15, 26, 6}, {17, 29, 16, 24} };
  for (int i = 0; i < 5; ++i) {
    for (int r = 0; r < 4; ++r) {
      x0 += x1;
      x1 = rotl32(x1, rot[i & 1][r]);
      x1 ^= x0;
    }
    x0 += ks[(i + 1) % 3];
    x1 += ks[(i + 2) % 3] + (uint32_t)(i + 1);
  }
  return { x0, x1 };
}

// jax_threefry_partitionable split: nk_j = full threefry(key, (0, j))
constexpr TF2 SPA = threefry(0u, 42u, 0u, 0u);
constexpr TF2 SPB = threefry(0u, 42u, 0u, 1u);
constexpr uint32_t NK1_0 = SPA.a, NK1_1 = SPA.b;
constexpr uint32_t NK2_0 = SPB.a, NK2_1 = SPB.b;

// partitionable random_bits(32): bits = y0 ^ y1 of threefry(key, 0, i)
__device__ inline float gumbel_elem(uint32_t k0, uint32_t k1, uint32_t i) {
  TF2 t = threefry(k0, k1, 0u, i);
  uint32_t bits = t.a ^ t.b;
  float f = __uint_as_float((bits >> 9) | 0x3f800000u) - 1.0f;
  float u = fmaxf(1.1754943508222875e-38f, f + 1.1754943508222875e-38f);
  return -__logf(-__logf(u));   // v_log_f32: ~1 ulp, plenty for 2e-2 budget
}

__device__ inline unsigned short f2bf_rne(float f) {
  uint32_t u = __float_as_uint(f);
  uint32_t r = (u + 0x7fffu + ((u >> 16) & 1u)) >> 16;
  return (unsigned short)r;
}

// ---------------- pass 1: per-node partial MLP, 8-way split ----------------
// block -> (p, q): p = half (A: +b1 / B), q = quarter of HID (16 outputs).
// Each thread: one node, 16 outputs. Weight addrs wave-uniform -> s_load.
#define NBLK_V 196  // ceil(50000/256)

__global__ __launch_bounds__(256, 4)
void node_q_kernel(const float* __restrict__ node,
                   const float* __restrict__ W1,
                   const float* __restrict__ b1,
                   unsigned short* __restrict__ A_tab,
                   unsigned short* __restrict__ B_tab) {
  const int pq = blockIdx.x / NBLK_V;          // 0..7, wave-uniform
  const int p  = pq >> 2;
  const int q  = pq & 3;
  const int v  = (blockIdx.x % NBLK_V) * blockDim.x + threadIdx.x;
  if (v >= N_NODES) return;

  const float4* __restrict__ xp = (const float4*)(node + (size_t)v * DIM);
  const float*  __restrict__ Wb = W1 + ((size_t)p * DIM) * HID + q * 16;

  float acc[16];
  if (p == 0) {
#pragma unroll
    for (int j = 0; j < 16; ++j) acc[j] = b1[q * 16 + j];
  } else {
#pragma unroll
    for (int j = 0; j < 16; ++j) acc[j] = 0.0f;
  }

#pragma unroll 4
  for (int dd = 0; dd < DIM / 4; ++dd) {
    const float4 x4 = xp[dd];
    const float xs[4] = { x4.x, x4.y, x4.z, x4.w };
#pragma unroll
    for (int k = 0; k < 4; ++k) {
      const float x = xs[k];
      const float4* __restrict__ wrow =
          (const float4*)(Wb + (size_t)(dd * 4 + k) * HID);
#pragma unroll
      for (int j4 = 0; j4 < 4; ++j4) {
        const float4 w = wrow[j4];
        acc[4 * j4 + 0] = fmaf(x, w.x, acc[4 * j4 + 0]);
        acc[4 * j4 + 1] = fmaf(x, w.y, acc[4 * j4 + 1]);
        acc[4 * j4 + 2] = fmaf(x, w.z, acc[4 * j4 + 2]);
        acc[4 * j4 + 3] = fmaf(x, w.w, acc[4 * j4 + 3]);
      }
    }
  }

  unsigned short* dst = (p ? B_tab : A_tab) + (size_t)v * HID + q * 16;
#pragma unroll
  for (int h = 0; h < 2; ++h) {
    union { unsigned short us[8]; uint4 u4; } pk;
#pragma unroll
    for (int t = 0; t < 8; ++t) pk.us[t] = f2bf_rne(acc[h * 8 + t]);
    ((uint4*)dst)[h] = pk.u4;
  }
}

// ---------------- pass 2: 2 edges/thread, all gathers issued up front ------
__global__ __launch_bounds__(256, 4)
void edge_kernel2(const int* __restrict__ ei,
                  const unsigned short* __restrict__ A_tab,
                  const unsigned short* __restrict__ B_tab,
                  const float* __restrict__ W2,
                  const float* __restrict__ b2,
                  float* __restrict__ out) {
  const int t  = blockIdx.x * blockDim.x + threadIdx.x;  // 0..799999
  const int e0 = 2 * t;

  const int2 rr = *(const int2*)(ei + e0);        // rows for e0, e0+1
  const int2 cc = *(const int2*)(ei + NE + e0);   // cols for e0, e0+1

  const uint4* __restrict__ a0 = (const uint4*)(A_tab + (size_t)rr.x * HID);
  const uint4* __restrict__ a1 = (const uint4*)(A_tab + (size_t)rr.y * HID);
  const uint4* __restrict__ b0 = (const uint4*)(B_tab + (size_t)cc.x * HID);
  const uint4* __restrict__ b1 = (const uint4*)(B_tab + (size_t)cc.y * HID);

  uint4 A0[8], B0[8], A1[8], B1[8];
#pragma unroll
  for (int q = 0; q < 8; ++q) { A0[q] = a0[q]; B0[q] = b0[q]; }
#pragma unroll
  for (int q = 0; q < 8; ++q) { A1[q] = a1[q]; B1[q] = b1[q]; }

  float acc0 = 0.0f, acc1 = 0.0f;
#pragma unroll
  for (int q = 0; q < 8; ++q) {
    const uint32_t* au0 = (const uint32_t*)&A0[q];
    const uint32_t* bu0 = (const uint32_t*)&B0[q];
    const uint32_t* au1 = (const uint32_t*)&A1[q];
    const uint32_t* bu1 = (const uint32_t*)&B1[q];
#pragma unroll
    for (int k = 0; k < 4; ++k) {
      const int j = q * 8 + k * 2;
      const float wlo = W2[j], whi = W2[j + 1];   // wave-uniform -> s_load
      {
        const float alo = __uint_as_float(au0[k] << 16);
        const float ahi = __uint_as_float(au0[k] & 0xffff0000u);
        const float blo = __uint_as_float(bu0[k] << 16);
        const float bhi = __uint_as_float(bu0[k] & 0xffff0000u);
        acc0 = fmaf(fmaxf(alo + blo, 0.0f), wlo, acc0);
        acc0 = fmaf(fmaxf(ahi + bhi, 0.0f), whi, acc0);
      }
      {
        const float alo = __uint_as_float(au1[k] << 16);
        const float ahi = __uint_as_float(au1[k] & 0xffff0000u);
        const float blo = __uint_as_float(bu1[k] << 16);
        const float bhi = __uint_as_float(bu1[k] & 0xffff0000u);
        acc1 = fmaf(fmaxf(alo + blo, 0.0f), wlo, acc1);
        acc1 = fmaf(fmaxf(ahi + bhi, 0.0f), whi, acc1);
      }
    }
  }

  const float bias2 = b2[0];
  const float z0 = acc0 + bias2 + gumbel_elem(NK1_0, NK1_1, (uint32_t)e0)
                               - gumbel_elem(NK2_0, NK2_1, (uint32_t)e0);
  const float z1 = acc1 + bias2 + gumbel_elem(NK1_0, NK1_1, (uint32_t)(e0 + 1))
                               - gumbel_elem(NK2_0, NK2_1, (uint32_t)(e0 + 1));

  float2 o;
  o.x = __frcp_rn(1.0f + __expf(-z0));
  o.y = __frcp_rn(1.0f + __expf(-z1));
  *(float2*)(out + e0) = o;
}

// ---------------- fallback (fused, no workspace) ----------------
__global__ __launch_bounds__(256, 4)
void edge_prune_fallback(const float* __restrict__ node,
                         const int*   __restrict__ ei,
                         const float* __restrict__ W1,
                         const float* __restrict__ b1,
                         const float* __restrict__ W2,
                         const float* __restrict__ b2,
                         float*       __restrict__ out) {
  const int tid    = blockIdx.x * blockDim.x + threadIdx.x;
  const int stride = gridDim.x * blockDim.x;
  const float bias2 = b2[0];

  for (int e = tid; e < NE; e += stride) {
    const int r = ei[e];
    const int c = ei[NE + e];
    const float4* __restrict__ up = (const float4*)(node + (size_t)r * DIM);
    const float4* __restrict__ vp = (const float4*)(node + (size_t)c * DIM);

    float h[HID];
#pragma unroll
    for (int j = 0; j < HID; ++j) h[j] = b1[j];

#pragma unroll 1
    for (int dd = 0; dd < DIM / 4; ++dd) {
      const float4 xu = up[dd];
      const float4 xv = vp[dd];
      const float xs[8] = { xu.x, xu.y, xu.z, xu.w, xv.x, xv.y, xv.z, xv.w };
#pragma unroll
      for (int k = 0; k < 8; ++k) {
        const int drow = (k < 4) ? (dd * 4 + k) : (DIM + dd * 4 + (k - 4));
        const float4* __restrict__ wrow = (const float4*)(W1 + drow * HID);
        const float x = xs[k];
#pragma unroll
        for (int j4 = 0; j4 < HID / 4; ++j4) {
          const float4 w = wrow[j4];
          h[j4 * 4 + 0] = fmaf(x, w.x, h[j4 * 4 + 0]);
          h[j4 * 4 + 1] = fmaf(x, w.y, h[j4 * 4 + 1]);
          h[j4 * 4 + 2] = fmaf(x, w.z, h[j4 * 4 + 2]);
          h[j4 * 4 + 3] = fmaf(x, w.w, h[j4 * 4 + 3]);
        }
      }
    }

    float logit = bias2;
#pragma unroll
    for (int j = 0; j < HID; ++j) logit = fmaf(fmaxf(h[j], 0.0f), W2[j], logit);

    const float g1 = gumbel_elem(NK1_0, NK1_1, (uint32_t)e);
    const float g2 = gumbel_elem(NK2_0, NK2_1, (uint32_t)e);
    const float z  = logit + g1 - g2;
    out[e] = 1.0f / (1.0f + __expf(-z));
  }
}

extern "C" void kernel_launch(void* const* d_in, const int* in_sizes, int n_in,
                              void* d_out, int out_size, void* d_ws, size_t ws_size,
                              hipStream_t stream) {
  const float* node = (const float*)d_in[0];
  const int*   ei   = (const int*)  d_in[1];
  const float* W1   = (const float*)d_in[2];
  const float* b1   = (const float*)d_in[3];
  const float* W2   = (const float*)d_in[4];
  const float* b2   = (const float*)d_in[5];
  float* out = (float*)d_out;

  const size_t tab_bytes = (size_t)N_NODES * HID * sizeof(unsigned short);  // 6.4 MB
  if (ws_size >= 2 * tab_bytes) {
    unsigned short* A_tab = (unsigned short*)d_ws;
    unsigned short* B_tab = A_tab + (size_t)N_NODES * HID;
    // pass 1: 8 * 196 = 1568 blocks, one node x 16 outputs per thread
    node_q_kernel<<<dim3(8 * NBLK_V), dim3(256), 0, stream>>>(
        node, W1, b1, A_tab, B_tab);
    // pass 2: exact tiling, 2 edges/thread: 3125 * 256 * 2 = 1,600,000
    edge_kernel2<<<dim3(NE / 512), dim3(256), 0, stream>>>(
        ei, A_tab, B_tab, W2, b2, out);
  } else {
    edge_prune_fallback<<<dim3(1024), dim3(256), 0, stream>>>(
        node, ei, W1, b1, W2, b2, out);
  }
}

// Round 5
// 98.353 us; speedup vs baseline: 1.9328x; 1.9328x over previous
//
#include <hip/hip_runtime.h>
#include <hip/hip_bf16.h>
#include <stdint.h>

#define N_NODES 50000
#define NE      1600000
#define DIM     128
#define HID     64

// ---------------- JAX threefry2x32 core (bit-exact) ----------------
struct TF2 { uint32_t a, b; };

__host__ __device__ constexpr uint32_t rotl32(uint32_t x, int d) {
  return (x << d) | (x >> (32 - d));
}

__host__ __device__ constexpr TF2 threefry(uint32_t k0, uint32_t k1,
                                           uint32_t c0, uint32_t c1) {
  uint32_t ks[3] = { k0, k1, k0 ^ k1 ^ 0x1BD11BDAu };
  uint32_t x0 = c0 + ks[0], x1 = c1 + ks[1];
  const int rot[2][4] = { {13, 15, 26, 6}, {17, 29, 16, 24} };
  for (int i = 0; i < 5; ++i) {
    for (int r = 0; r < 4; ++r) {
      x0 += x1;
      x1 = rotl32(x1, rot[i & 1][r]);
      x1 ^= x0;
    }
    x0 += ks[(i + 1) % 3];
    x1 += ks[(i + 2) % 3] + (uint32_t)(i + 1);
  }
  return { x0, x1 };
}

// jax_threefry_partitionable split: nk_j = full threefry(key, (0, j))
constexpr TF2 SPA = threefry(0u, 42u, 0u, 0u);
constexpr TF2 SPB = threefry(0u, 42u, 0u, 1u);
constexpr uint32_t NK1_0 = SPA.a, NK1_1 = SPA.b;
constexpr uint32_t NK2_0 = SPB.a, NK2_1 = SPB.b;

// partitionable random_bits(32): bits = y0 ^ y1 of threefry(key, 0, i)
__device__ inline float gumbel_elem(uint32_t k0, uint32_t k1, uint32_t i) {
  TF2 t = threefry(k0, k1, 0u, i);
  uint32_t bits = t.a ^ t.b;
  float f = __uint_as_float((bits >> 9) | 0x3f800000u) - 1.0f;
  float u = fmaxf(1.1754943508222875e-38f, f + 1.1754943508222875e-38f);
  return -__logf(-__logf(u));   // v_log_f32 ~1 ulp; budget is 2e-2
}

__device__ inline unsigned short f2bf_rne(float f) {
  uint32_t u = __float_as_uint(f);
  uint32_t r = (u + 0x7fffu + ((u >> 16) & 1u)) >> 16;
  return (unsigned short)r;
}

// ---------------- pass 1: node partials, cooperative 32-node blocks --------
// Block = 256 threads: lane j = tid&63 owns output column j (both halves),
// g = tid>>6 picks 8 of the block's 32 nodes. x rows staged in LDS (16 KB),
// read back as broadcasts; W1[dd][j] reads are wave-coalesced 256 B (L1-hot).
// Node table is read exactly once (25.6 MB).
#define NPB   32
#define NBLKN ((N_NODES + NPB - 1) / NPB)   // 1563

__global__ __launch_bounds__(256, 4)
void node_coop_kernel(const float* __restrict__ node,
                      const float* __restrict__ W1,
                      const float* __restrict__ b1,
                      unsigned short* __restrict__ A_tab,
                      unsigned short* __restrict__ B_tab) {
  __shared__ float4 xs_lds[NPB * (DIM / 4)];   // 32 rows x 32 float4 = 16 KB

  const int j  = threadIdx.x & 63;
  const int g  = threadIdx.x >> 6;
  const int v0 = blockIdx.x * NPB;

  // cooperative staging: 1024 float4s, 4 per thread, coalesced
  {
    const float4* __restrict__ src = (const float4*)(node + (size_t)v0 * DIM);
    const int lim = (N_NODES - v0) * (DIM / 4);  // valid float4 count
#pragma unroll
    for (int t = 0; t < 4; ++t) {
      const int idx = threadIdx.x + t * 256;
      xs_lds[idx] = (idx < lim) ? src[idx] : make_float4(0.f, 0.f, 0.f, 0.f);
    }
  }
  __syncthreads();

  float accA[8], accB[8];
  const float bj = b1[j];
#pragma unroll
  for (int n = 0; n < 8; ++n) { accA[n] = bj; accB[n] = 0.0f; }

#pragma unroll 2
  for (int t4 = 0; t4 < DIM / 4; ++t4) {
    const int dd = t4 * 4;
    const float wa0 = W1[(size_t)(dd + 0) * HID + j];
    const float wa1 = W1[(size_t)(dd + 1) * HID + j];
    const float wa2 = W1[(size_t)(dd + 2) * HID + j];
    const float wa3 = W1[(size_t)(dd + 3) * HID + j];
    const float wb0 = W1[(size_t)(DIM + dd + 0) * HID + j];
    const float wb1 = W1[(size_t)(DIM + dd + 1) * HID + j];
    const float wb2 = W1[(size_t)(DIM + dd + 2) * HID + j];
    const float wb3 = W1[(size_t)(DIM + dd + 3) * HID + j];
#pragma unroll
    for (int n = 0; n < 8; ++n) {
      const float4 xs = xs_lds[(g * 8 + n) * (DIM / 4) + t4];  // LDS broadcast
      accA[n] = fmaf(xs.x, wa0, accA[n]);
      accA[n] = fmaf(xs.y, wa1, accA[n]);
      accA[n] = fmaf(xs.z, wa2, accA[n]);
      accA[n] = fmaf(xs.w, wa3, accA[n]);
      accB[n] = fmaf(xs.x, wb0, accB[n]);
      accB[n] = fmaf(xs.y, wb1, accB[n]);
      accB[n] = fmaf(xs.z, wb2, accB[n]);
      accB[n] = fmaf(xs.w, wb3, accB[n]);
    }
  }

#pragma unroll
  for (int n = 0; n < 8; ++n) {
    const int v = v0 + g * 8 + n;
    if (v < N_NODES) {
      A_tab[(size_t)v * HID + j] = f2bf_rne(accA[n]);  // 128 B/row per wave
      B_tab[(size_t)v * HID + j] = f2bf_rne(accB[n]);
    }
  }
}

// ---------------- pass 2: round-3 edge kernel, occupancy cap 4 -> 6 --------
__global__ __launch_bounds__(256, 6)
void edge_kernel(const int* __restrict__ ei,
                 const unsigned short* __restrict__ A_tab,
                 const unsigned short* __restrict__ B_tab,
                 const float* __restrict__ W2,
                 const float* __restrict__ b2,
                 float* __restrict__ out) {
  const int tid    = blockIdx.x * blockDim.x + threadIdx.x;
  const int stride = gridDim.x * blockDim.x;
  const float bias2 = b2[0];

  for (int e = tid; e < NE; e += stride) {
    const int r = ei[e];
    const int c = ei[NE + e];
    const uint4* __restrict__ ap = (const uint4*)(A_tab + (size_t)r * HID);
    const uint4* __restrict__ bp = (const uint4*)(B_tab + (size_t)c * HID);

    uint4 av[8], bv[8];
#pragma unroll
    for (int q = 0; q < 8; ++q) av[q] = ap[q];
#pragma unroll
    for (int q = 0; q < 8; ++q) bv[q] = bp[q];

    float logit = bias2;
#pragma unroll
    for (int q = 0; q < 8; ++q) {
      const uint32_t* au = (const uint32_t*)&av[q];
      const uint32_t* bu = (const uint32_t*)&bv[q];
#pragma unroll
      for (int t = 0; t < 4; ++t) {
        const float a0 = __uint_as_float(au[t] << 16);
        const float a1 = __uint_as_float(au[t] & 0xffff0000u);
        const float b0 = __uint_as_float(bu[t] << 16);
        const float b1v = __uint_as_float(bu[t] & 0xffff0000u);
        const int jj = q * 8 + t * 2;
        logit = fmaf(fmaxf(a0 + b0, 0.0f),  W2[jj],     logit);
        logit = fmaf(fmaxf(a1 + b1v, 0.0f), W2[jj + 1], logit);
      }
    }

    const float g1 = gumbel_elem(NK1_0, NK1_1, (uint32_t)e);
    const float g2 = gumbel_elem(NK2_0, NK2_1, (uint32_t)e);
    const float z  = logit + g1 - g2;  // TEMP = 1.0
    out[e] = 1.0f / (1.0f + __expf(-z));
  }
}

// ---------------- fallback (fused, no workspace) ----------------
__global__ __launch_bounds__(256, 4)
void edge_prune_fallback(const float* __restrict__ node,
                         const int*   __restrict__ ei,
                         const float* __restrict__ W1,
                         const float* __restrict__ b1,
                         const float* __restrict__ W2,
                         const float* __restrict__ b2,
                         float*       __restrict__ out) {
  const int tid    = blockIdx.x * blockDim.x + threadIdx.x;
  const int stride = gridDim.x * blockDim.x;
  const float bias2 = b2[0];

  for (int e = tid; e < NE; e += stride) {
    const int r = ei[e];
    const int c = ei[NE + e];
    const float4* __restrict__ up = (const float4*)(node + (size_t)r * DIM);
    const float4* __restrict__ vp = (const float4*)(node + (size_t)c * DIM);

    float h[HID];
#pragma unroll
    for (int j = 0; j < HID; ++j) h[j] = b1[j];

#pragma unroll 1
    for (int dd = 0; dd < DIM / 4; ++dd) {
      const float4 xu = up[dd];
      const float4 xv = vp[dd];
      const float xs[8] = { xu.x, xu.y, xu.z, xu.w, xv.x, xv.y, xv.z, xv.w };
#pragma unroll
      for (int k = 0; k < 8; ++k) {
        const int drow = (k < 4) ? (dd * 4 + k) : (DIM + dd * 4 + (k - 4));
        const float4* __restrict__ wrow = (const float4*)(W1 + drow * HID);
        const float x = xs[k];
#pragma unroll
        for (int j4 = 0; j4 < HID / 4; ++j4) {
          const float4 w = wrow[j4];
          h[j4 * 4 + 0] = fmaf(x, w.x, h[j4 * 4 + 0]);
          h[j4 * 4 + 1] = fmaf(x, w.y, h[j4 * 4 + 1]);
          h[j4 * 4 + 2] = fmaf(x, w.z, h[j4 * 4 + 2]);
          h[j4 * 4 + 3] = fmaf(x, w.w, h[j4 * 4 + 3]);
        }
      }
    }

    float logit = bias2;
#pragma unroll
    for (int j = 0; j < HID; ++j) logit = fmaf(fmaxf(h[j], 0.0f), W2[j], logit);

    const float g1 = gumbel_elem(NK1_0, NK1_1, (uint32_t)e);
    const float g2 = gumbel_elem(NK2_0, NK2_1, (uint32_t)e);
    const float z  = logit + g1 - g2;
    out[e] = 1.0f / (1.0f + __expf(-z));
  }
}

extern "C" void kernel_launch(void* const* d_in, const int* in_sizes, int n_in,
                              void* d_out, int out_size, void* d_ws, size_t ws_size,
                              hipStream_t stream) {
  const float* node = (const float*)d_in[0];
  const int*   ei   = (const int*)  d_in[1];
  const float* W1   = (const float*)d_in[2];
  const float* b1   = (const float*)d_in[3];
  const float* W2   = (const float*)d_in[4];
  const float* b2   = (const float*)d_in[5];
  float* out = (float*)d_out;

  const size_t tab_bytes = (size_t)N_NODES * HID * sizeof(unsigned short);  // 6.4 MB
  if (ws_size >= 2 * tab_bytes) {
    unsigned short* A_tab = (unsigned short*)d_ws;
    unsigned short* B_tab = A_tab + (size_t)N_NODES * HID;
    // pass 1: 1563 blocks x 32 nodes; node table read once
    node_coop_kernel<<<dim3(NBLKN), dim3(256), 0, stream>>>(
        node, W1, b1, A_tab, B_tab);
    // pass 2: one full generation at 6 blocks/CU; ~4 edges/thread grid-stride
    edge_kernel<<<dim3(1536), dim3(256), 0, stream>>>(
        ei, A_tab, B_tab, W2, b2, out);
  } else {
    edge_prune_fallback<<<dim3(1024), dim3(256), 0, stream>>>(
        node, ei, W1, b1, W2, b2, out);
  }
}